// Round 6
// baseline (247.739 us; speedup 1.0000x reference)
//
#include <hip/hip_runtime.h>
#include <hip/hip_bf16.h>

#define NL 2
// B=32, K=64, D=256, LS=128, rows = B*K = 2048

using bf16 = __hip_bfloat16;
typedef short bf16x8 __attribute__((ext_vector_type(8)));
typedef float f32x4 __attribute__((ext_vector_type(4)));

__device__ __forceinline__ float bfu(unsigned short u) { return __uint_as_float(((unsigned)u) << 16); }

__device__ __forceinline__ unsigned short bfr(float v) {   // RNE fp32->bf16 bits
  unsigned u = __float_as_uint(v);
  u += 0x7FFFu + ((u >> 16) & 1u);
  return (unsigned short)(u >> 16);
}

// exact gelu for the low-volume spots
__device__ __forceinline__ float gelu_e(float x) {
  return 0.5f * x * (1.0f + erff(x * 0.7071067811865475f));
}

__device__ __forceinline__ float load_f(const void* p, int i, int fl) {
  if (fl) return bfu(((const unsigned short*)p)[i]);
  return ((const float*)p)[i];
}

// split fp32x8 into bf16 hi + lo fragments
__device__ __forceinline__ void split8(const float4 v0, const float4 v1, bf16x8& hi, bf16x8& lo) {
  float vs[8] = {v0.x, v0.y, v0.z, v0.w, v1.x, v1.y, v1.z, v1.w};
  #pragma unroll
  for (int i = 0; i < 8; ++i) {
    unsigned short h = bfr(vs[i]);
    hi[i] = (short)h;
    lo[i] = (short)bfr(vs[i] - bfu(h));
  }
}

// ---------------------------------------------------------------------------
__global__ __launch_bounds__(256) void detect_kernel(const void* __restrict__ X, int* __restrict__ flag) {
  __shared__ int bad;
  if (threadIdx.x == 0) bad = 0;
  __syncthreads();
  const unsigned short h = ((const unsigned short*)X)[threadIdx.x];
  const float v = bfu(h);
  if (!(fabsf(v) < 1e6f)) atomicOr(&bad, 1);
  __syncthreads();
  if (threadIdx.x == 0) *flag = bad ? 0 : 1;    // 1 = inputs are bf16
}

// ---------------------------------------------------------------------------
// prep v2: coalesced LDS-transpose conversion.
// blocks: [0,16)   A: wfb frags, (l,kt)
//         [16,64)  B: w3b frags, (l,gm,kt)
//         [64,320) C: x convert
//         [320,344)D: wh transposes
//         344      E: bc biases
// ---------------------------------------------------------------------------
__global__ __launch_bounds__(256) void prep_kernel(
    const void* __restrict__ X, const void* __restrict__ kw, const void* __restrict__ qw,
    const void* __restrict__ rw1, const void* __restrict__ rw2, const void* __restrict__ mw1,
    const void* __restrict__ mw2, const void* __restrict__ pw, const void* __restrict__ muw,
    const void* __restrict__ spw,
    const void* __restrict__ rb1, const void* __restrict__ rb2, const void* __restrict__ lng,
    const void* __restrict__ lnb, const void* __restrict__ mb1, const void* __restrict__ mb2,
    const void* __restrict__ pb, const void* __restrict__ mub, const void* __restrict__ spb,
    const int* __restrict__ flag,
    float* __restrict__ x, unsigned short* __restrict__ wfb, unsigned short* __restrict__ w3b,
    float* __restrict__ wh, float* __restrict__ bc)
{
  __shared__ __align__(16) char psm[65536];
  const int fl = *flag;
  const int t = threadIdx.x;
  int blk = blockIdx.x;

  if (blk < 16) {   // ---- A: wfb (l,kt); LDS = 4 segs x 256 e x 32 d bf16-bits
    unsigned short* ls = (unsigned short*)psm;
    unsigned* lsu = (unsigned*)psm;
    const int l = blk >> 3, kt = blk & 7;
    if (fl) {
      #pragma unroll
      for (int s = 0; s < 4; ++s) {
        const unsigned* sp = (const unsigned*)((s == 0) ? kw : (s == 1) ? qw : rw1);
        const int rstr = (s < 2) ? 128 : 256;
        const int coff = ((s == 3) ? 128 : 0) + kt*16;
        for (int i = t; i < 4096; i += 256) {
          const int e = i >> 4, d2 = i & 15;
          lsu[s*4096 + i] = sp[(l*256 + e)*rstr + coff + d2];
        }
      }
    } else {
      #pragma unroll
      for (int s = 0; s < 4; ++s) {
        const float* sp = (const float*)((s == 0) ? kw : (s == 1) ? qw : rw1);
        const int rstr = (s < 2) ? 256 : 512;
        const int coff = ((s == 3) ? 256 : 0) + kt*32;
        for (int i = t; i < 4096; i += 256) {
          const int e = i >> 4, d2 = i & 15;
          const float f0 = sp[(l*256 + e)*rstr + coff + d2*2];
          const float f1 = sp[(l*256 + e)*rstr + coff + d2*2 + 1];
          lsu[s*4096 + i] = (unsigned)bfr(f0) | ((unsigned)bfr(f1) << 16);
        }
      }
    }
    __syncthreads();
    unsigned* outp = (unsigned*)wfb + (l*8 + kt)*16384;
    for (int f2 = t; f2 < 16384; f2 += 256) {
      const int j2 = f2 & 3, lane = (f2 >> 2) & 63, ntg = f2 >> 8;
      const int seg = ntg >> 4;
      const int e = (ntg & 15)*16 + (lane & 15);
      const int dl = ((lane >> 4) & 3)*8 + j2*2;
      unsigned short r0 = ls[seg*8192 + e*32 + dl];
      unsigned short r1 = ls[seg*8192 + e*32 + dl + 1];
      if (seg == 1) { r0 = bfr(bfu(r0)*0.0625f); r1 = bfr(bfu(r1)*0.0625f); }
      else if (seg == 2) {
        const unsigned short w0 = ls[3*8192 + e*32 + dl];
        const unsigned short w1 = ls[3*8192 + e*32 + dl + 1];
        r0 = bfr(bfu(r0) + bfu(w0)); r1 = bfr(bfu(r1) + bfu(w1));
      }
      outp[f2] = (unsigned)r0 | ((unsigned)r1 << 16);
    }
    return;
  }
  blk -= 16;
  if (blk < 48) {   // ---- B: w3b (l,gm,kt)
    unsigned short* ls = (unsigned short*)psm;
    unsigned* lsu = (unsigned*)psm;
    const int l3 = blk >> 3, kt = blk & 7;
    const int l = l3 / 3, gm = l3 % 3;
    const void* src = (gm == 0) ? rw2 : (gm == 1) ? mw1 : mw2;
    if (fl) {
      const unsigned* sp = (const unsigned*)src;
      for (int i = t; i < 4096; i += 256) {
        const int e = i >> 4, d2 = i & 15;
        lsu[i] = sp[(l*256 + e)*128 + kt*16 + d2];
      }
    } else {
      const float* sp = (const float*)src;
      for (int i = t; i < 4096; i += 256) {
        const int e = i >> 4, d2 = i & 15;
        const float f0 = sp[(l*256 + e)*256 + kt*32 + d2*2];
        const float f1 = sp[(l*256 + e)*256 + kt*32 + d2*2 + 1];
        lsu[i] = (unsigned)bfr(f0) | ((unsigned)bfr(f1) << 16);
      }
    }
    __syncthreads();
    unsigned* outp = (unsigned*)w3b + (l3*8 + kt)*4096;
    for (int f2 = t; f2 < 4096; f2 += 256) {
      const int j2 = f2 & 3, lane = (f2 >> 2) & 63, nt = f2 >> 8;
      const int e = nt*16 + (lane & 15);
      const int dl = ((lane >> 4) & 3)*8 + j2*2;
      outp[f2] = (unsigned)ls[e*32 + dl] | ((unsigned)ls[e*32 + dl + 1] << 16);
    }
    return;
  }
  blk -= 48;
  if (blk < 256) {  // ---- C: x
    if (fl) {
      const unsigned* Xu = (const unsigned*)X;
      for (int i = t; i < 1024; i += 256) {
        const unsigned u = Xu[blk*1024 + i];
        float2 v;
        v.x = __uint_as_float(u << 16);
        v.y = __uint_as_float(u & 0xffff0000u);
        *(float2*)&x[blk*2048 + i*2] = v;
      }
    } else {
      const float* Xf = (const float*)X;
      for (int i = t; i < 2048; i += 256) x[blk*2048 + i] = Xf[blk*2048 + i];
    }
    return;
  }
  blk -= 256;
  if (blk < 24) {   // ---- D: wh transposes
    float* lsf = (float*)psm;
    if (blk < 8) {          // projT: wh[d*128 + l]
      const int l0 = blk*16;
      if (fl) {
        const unsigned* sp = (const unsigned*)pw;
        for (int i = t; i < 2048; i += 256) {
          const int ll = i >> 7, d2 = i & 127;
          const unsigned u = sp[(l0 + ll)*128 + d2];
          lsf[ll*256 + d2*2]     = __uint_as_float(u << 16);
          lsf[ll*256 + d2*2 + 1] = __uint_as_float(u & 0xffff0000u);
        }
      } else {
        const float* sp = (const float*)pw;
        for (int i = t; i < 4096; i += 256) {
          const int ll = i >> 8, d = i & 255;
          lsf[ll*256 + d] = sp[(l0 + ll)*256 + d];
        }
      }
      __syncthreads();
      for (int i = t; i < 4096; i += 256) {
        const int d = i >> 4, ll = i & 15;
        wh[d*128 + l0 + ll] = lsf[ll*256 + d];
      }
    } else {                // muT / spT: wh[off + c*128 + l]
      const int grp = blk - 8;
      const int isSp = grp >> 3;
      const int l0 = (grp & 7)*16;
      const void* src = isSp ? spw : muw;
      const int off = isSp ? 49152 : 32768;
      if (fl) {
        const unsigned* sp = (const unsigned*)src;
        for (int i = t; i < 1024; i += 256) {
          const int ll = i >> 6, c2 = i & 63;
          const unsigned u = sp[(l0 + ll)*64 + c2];
          lsf[ll*128 + c2*2]     = __uint_as_float(u << 16);
          lsf[ll*128 + c2*2 + 1] = __uint_as_float(u & 0xffff0000u);
        }
      } else {
        const float* sp = (const float*)src;
        for (int i = t; i < 2048; i += 256) {
          const int ll = i >> 7, c = i & 127;
          lsf[ll*128 + c] = sp[(l0 + ll)*128 + c];
        }
      }
      __syncthreads();
      for (int i = t; i < 2048; i += 256) {
        const int c = i >> 4, ll = i & 15;
        wh[off + c*128 + l0 + ll] = lsf[ll*128 + c];
      }
    }
    return;
  }
  // ---- E: bc
  for (int i = t; i < 3456; i += 256) {
    const void* src; int off;
    if (i < 512)       { src = rb1; off = i; }
    else if (i < 1024) { src = rb2; off = i - 512; }
    else if (i < 1536) { src = lng; off = i - 1024; }
    else if (i < 2048) { src = lnb; off = i - 1536; }
    else if (i < 2560) { src = mb1; off = i - 2048; }
    else if (i < 3072) { src = mb2; off = i - 2560; }
    else if (i < 3200) { src = pb;  off = i - 3072; }
    else if (i < 3328) { src = mub; off = i - 3200; }
    else               { src = spb; off = i - 3328; }
    bc[i] = load_f(src, off, fl);
  }
}

// ---------------------------------------------------------------------------
// k1: [k|q] -> kq fp32 [2048][512]; P(+rb1) -> Pf fp32 [2048][256];
//     Q -> Qpk packed bf16 [2048 rows][128 col-pairs] (row-major, j = row&63)
// MFMA split-A bf16; block 256 thr / 4 waves, tile M=16 x N=512; grid 256
// ---------------------------------------------------------------------------
__global__ __launch_bounds__(256) void k1_kqpq(
    const float* __restrict__ x, const unsigned short* __restrict__ wfb,
    const float* __restrict__ bc, float* __restrict__ kq, float* __restrict__ Pf,
    unsigned* __restrict__ Qpk, int l)
{
  __shared__ __align__(16) unsigned short aF[2][4096];
  const int t = threadIdx.x;
  const int mb = (int)blockIdx.x >> 1, nb = (int)blockIdx.x & 1;
  const int row0 = mb * 16;
  #pragma unroll
  for (int i = 0; i < 4; ++i) {
    const int c = t + i*256;
    const int row = c >> 6, d0 = (c & 63)*4;
    const float4 v = *(const float4*)&x[(row0 + row)*256 + d0];
    ushort4 h, lo;
    h.x = bfr(v.x); h.y = bfr(v.y); h.z = bfr(v.z); h.w = bfr(v.w);
    lo.x = bfr(v.x - bfu(h.x)); lo.y = bfr(v.y - bfu(h.y));
    lo.z = bfr(v.z - bfu(h.z)); lo.w = bfr(v.w - bfu(h.w));
    const int kt = d0 >> 5;
    const int lane = row | (((d0 >> 3) & 3) << 4);
    const int j = d0 & 7;
    *(ushort4*)&aF[0][kt*512 + lane*8 + j] = h;
    *(ushort4*)&aF[1][kt*512 + lane*8 + j] = lo;
  }
  __syncthreads();

  const int w = t >> 6, l64 = t & 63;
  const int col = l64 & 15, quad = l64 >> 4;
  f32x4 acc[8];
  #pragma unroll
  for (int i = 0; i < 8; ++i) acc[i] = (f32x4){0.f, 0.f, 0.f, 0.f};

  for (int kt = 0; kt < 8; ++kt) {
    const bf16x8 ah = *(const bf16x8*)&aF[0][kt*512 + l64*8];
    const bf16x8 al = *(const bf16x8*)&aF[1][kt*512 + l64*8];
    #pragma unroll
    for (int i = 0; i < 8; ++i) {
      const int ntg = nb*32 + w*8 + i;
      const bf16x8 b = *(const bf16x8*)&wfb[((l*8 + kt)*64 + ntg)*512 + l64*8];
      acc[i] = __builtin_amdgcn_mfma_f32_16x16x32_bf16(ah, b, acc[i], 0, 0, 0);
      acc[i] = __builtin_amdgcn_mfma_f32_16x16x32_bf16(al, b, acc[i], 0, 0, 0);
    }
  }
  #pragma unroll
  for (int i = 0; i < 8; ++i) {
    const int ntg = nb*32 + w*8 + i;
    if (ntg < 32) {                       // k | q -> kq
      const int n = ntg*16 + col;
      #pragma unroll
      for (int r = 0; r < 4; ++r)
        kq[(row0 + quad*4 + r)*512 + n] = acc[i][r];
    } else if (ntg < 48) {                // P -> Pf (+rb1)
      const int c = (ntg - 32)*16 + col;
      const float bias = bc[l*256 + c];
      #pragma unroll
      for (int r = 0; r < 4; ++r)
        Pf[(row0 + quad*4 + r)*256 + c] = acc[i][r] + bias;
    } else {                              // Q -> Qpk (packed bf16 pairs)
      #pragma unroll
      for (int r = 0; r < 4; ++r) {
        const float v = acc[i][r];
        const float pv = __shfl_xor(v, 1, 64);
        if (!(col & 1)) {
          const unsigned uu = (unsigned)bfr(v) | ((unsigned)bfr(pv) << 16);
          const int row = row0 + quad*4 + r;
          Qpk[row*128 + (ntg - 48)*8 + (col >> 1)] = uu;
        }
      }
    }
  }
}

// ---------------------------------------------------------------------------
// ks: per-b scores S = q k^T via MFMA; k hi/lo frags split ONCE into LDS.
// grid 32, 256 thr / 4 waves (wave = m-tile). S/softmax overlay the same LDS.
// ---------------------------------------------------------------------------
__global__ __launch_bounds__(256) void ks_scores(
    const float* __restrict__ kq, float* __restrict__ attn)
{
  __shared__ __align__(16) char smem[65536];
  unsigned short* kf0 = (unsigned short*)smem;       // 16384 shorts
  unsigned short* kf1 = kf0 + 16384;
  const int b = blockIdx.x, base = b << 6;
  const int t = threadIdx.x, w = t >> 6, l64 = t & 63;
  const int col = l64 & 15, quad = l64 >> 4;

  for (int i = t; i < 2048; i += 256) {
    const int row = i >> 5, grp = i & 31;
    const int kt = grp >> 2, q4 = grp & 3;
    const float4 v0 = *(const float4*)&kq[(base + row)*512 + grp*8];
    const float4 v1 = *(const float4*)&kq[(base + row)*512 + grp*8 + 4];
    bf16x8 hi, lo; split8(v0, v1, hi, lo);
    const int lane = (row & 15) | (q4 << 4);
    const int nt = row >> 4;
    *(bf16x8*)&kf0[((kt*4 + nt)*64 + lane)*8] = hi;
    *(bf16x8*)&kf1[((kt*4 + nt)*64 + lane)*8] = lo;
  }
  __syncthreads();

  f32x4 acc[4];
  #pragma unroll
  for (int i = 0; i < 4; ++i) acc[i] = (f32x4){0.f, 0.f, 0.f, 0.f};
  const float* qrow = kq + (base + w*16 + col)*512 + 256;
  for (int kt = 0; kt < 8; ++kt) {
    const int doff = kt*32 + quad*8;
    bf16x8 ah, al;
    split8(*(const float4*)&qrow[doff], *(const float4*)&qrow[doff + 4], ah, al);
    #pragma unroll
    for (int nt = 0; nt < 4; ++nt) {
      const bf16x8 bh = *(const bf16x8*)&kf0[((kt*4 + nt)*64 + l64)*8];
      const bf16x8 bl = *(const bf16x8*)&kf1[((kt*4 + nt)*64 + l64)*8];
      acc[nt] = __builtin_amdgcn_mfma_f32_16x16x32_bf16(ah, bh, acc[nt], 0, 0, 0);
      acc[nt] = __builtin_amdgcn_mfma_f32_16x16x32_bf16(ah, bl, acc[nt], 0, 0, 0);
      acc[nt] = __builtin_amdgcn_mfma_f32_16x16x32_bf16(al, bh, acc[nt], 0, 0, 0);
    }
  }
  __syncthreads();   // done reading kf; overlay S
  float* S = (float*)smem;            // [64][68]
  float* mrow = S + 64*68;
  float* srow = mrow + 64;
  #pragma unroll
  for (int nt = 0; nt < 4; ++nt)
    #pragma unroll
    for (int r = 0; r < 4; ++r)
      S[(w*16 + quad*4 + r)*68 + nt*16 + col] = acc[nt][r];
  __syncthreads();
  if (t < 256) {
    const int row = t >> 2, part = t & 3;
    float m = -1e30f;
    for (int c = part*16; c < part*16 + 16; ++c) m = fmaxf(m, S[row*68 + c]);
    m = fmaxf(m, __shfl_xor(m, 1, 64));
    m = fmaxf(m, __shfl_xor(m, 2, 64));
    float s = 0.f;
    for (int c = part*16; c < part*16 + 16; ++c) s += __expf(S[row*68 + c] - m);
    s += __shfl_xor(s, 1, 64);
    s += __shfl_xor(s, 2, 64);
    if (part == 0) { mrow[row] = m; srow[row] = 1.f / s; }
  }
  __syncthreads();
  #pragma unroll
  for (int i = 0; i < 16; ++i) {
    const int idx = i*256 + t;
    const int row = idx >> 6, c = idx & 63;
    attn[b*4096 + idx] = __expf(S[row*68 + c] - mrow[row]) * srow[row];
  }
}

// ---------------------------------------------------------------------------
// k23_agg: g[b,i,:] = sum_j attn[b,i,j] * gelu_s(P_i - Q_j)
// grid 512 (b, 4 rows), 256 thr. Q packed bf16 in LDS; pure-register inner loop.
// ---------------------------------------------------------------------------
__global__ __launch_bounds__(256) void k23_agg(
    const float* __restrict__ Pf, const unsigned* __restrict__ Qpk,
    const float* __restrict__ attn, float* __restrict__ g)
{
  __shared__ unsigned qls[8192];    // [j 64][cp 128]
  __shared__ float als[256];        // [row 4][j 64]
  const int t = threadIdx.x;
  const int b = (int)blockIdx.x >> 4, rq = (int)blockIdx.x & 15;
  const int base = b << 6, i0 = rq*4;
  {
    const float4* src = (const float4*)(Qpk + (size_t)base*128);
    float4* dst = (float4*)qls;
    for (int i = t; i < 2048; i += 256) dst[i] = src[i];
  }
  als[t] = attn[b*4096 + (i0 + (t >> 6))*64 + (t & 63)];
  __syncthreads();

  const int rg = t >> 7, cp = t & 127;
  const int r0 = base + i0 + rg*2;
  const float2 P0 = *(const float2*)&Pf[r0*256 + cp*2];
  const float2 P1 = *(const float2*)&Pf[(r0 + 1)*256 + cp*2];
  const float A00 = -1.702f * P0.x, A01 = -1.702f * P0.y;
  const float A10 = -1.702f * P1.x, A11 = -1.702f * P1.y;
  const float* a0p = &als[(rg*2)*64];
  const float* a1p = &als[(rg*2 + 1)*64];
  float acc00 = 0.f, acc01 = 0.f, acc10 = 0.f, acc11 = 0.f;
  #pragma unroll 4
  for (int j = 0; j < 64; ++j) {
    const unsigned u = qls[j*128 + cp];
    const float w0 = a0p[j], w1 = a1p[j];
    const float q0 = __uint_as_float(u << 16);
    const float q1 = __uint_as_float(u & 0xffff0000u);
    const float s00 = __builtin_amdgcn_rcpf(1.f + __expf(fmaf(1.702f, q0, A00)));
    const float s01 = __builtin_amdgcn_rcpf(1.f + __expf(fmaf(1.702f, q1, A01)));
    const float s10 = __builtin_amdgcn_rcpf(1.f + __expf(fmaf(1.702f, q0, A10)));
    const float s11 = __builtin_amdgcn_rcpf(1.f + __expf(fmaf(1.702f, q1, A11)));
    acc00 = fmaf(w0 * (P0.x - q0), s00, acc00);
    acc01 = fmaf(w0 * (P0.y - q1), s01, acc01);
    acc10 = fmaf(w1 * (P1.x - q0), s10, acc10);
    acc11 = fmaf(w1 * (P1.y - q1), s11, acc11);
  }
  *(float2*)&g[r0*256 + cp*2]       = make_float2(acc00, acc01);
  *(float2*)&g[(r0 + 1)*256 + cp*2] = make_float2(acc10, acc11);
}

// ---------------------------------------------------------------------------
// k4: agg=g@rw2^T+rb2 ; h=LN(x+agg) ; x += mlp2(gelu(mlp1(h)))  (MFMA, 16 rows/block)
// ---------------------------------------------------------------------------
__device__ __forceinline__ void k4_gemm(
    f32x4 acc[4], const unsigned short aF[2][4096],
    const unsigned short* __restrict__ wg, int w, int l64)
{
  #pragma unroll
  for (int nt = 0; nt < 4; ++nt) acc[nt] = (f32x4){0.f, 0.f, 0.f, 0.f};
  for (int kt = 0; kt < 8; ++kt) {
    const bf16x8 ah = *(const bf16x8*)&aF[0][kt*512 + l64*8];
    const bf16x8 al = *(const bf16x8*)&aF[1][kt*512 + l64*8];
    #pragma unroll
    for (int nt = 0; nt < 4; ++nt) {
      const bf16x8 b = *(const bf16x8*)&wg[((kt*16 + (w*4 + nt))*64 + l64)*8];
      acc[nt] = __builtin_amdgcn_mfma_f32_16x16x32_bf16(ah, b, acc[nt], 0, 0, 0);
      acc[nt] = __builtin_amdgcn_mfma_f32_16x16x32_bf16(al, b, acc[nt], 0, 0, 0);
    }
  }
}

__global__ __launch_bounds__(256) void k4_mix(
    const float* __restrict__ g, const unsigned short* __restrict__ w3b,
    const float* __restrict__ bc, float* __restrict__ x, int l)
{
  __shared__ __align__(16) unsigned short aF[2][4096];
  __shared__ float bufB[16*260];
  __shared__ float mv[16][2];
  const int t = threadIdx.x;
  const int row0 = blockIdx.x * 16;
  const int w = t >> 6, l64 = t & 63;
  const int col = l64 & 15, quad = l64 >> 4;
  const float* rb2c = bc + 512  + l*256;
  const float* lngc = bc + 1024 + l*256;
  const float* lnbc = bc + 1536 + l*256;
  const float* mb1c = bc + 2048 + l*256;
  const float* mb2c = bc + 2560 + l*256;
  const unsigned short* wg = w3b + l*3*65536;

  float xtr[4][4];
  #pragma unroll
  for (int nt = 0; nt < 4; ++nt)
    #pragma unroll
    for (int r = 0; r < 4; ++r)
      xtr[nt][r] = x[(row0 + quad*4 + r)*256 + (w*4 + nt)*16 + col];

  #pragma unroll
  for (int i = 0; i < 4; ++i) {
    const int c = t + i*256;
    const int row = c >> 6, d0 = (c & 63)*4;
    const float4 v = *(const float4*)&g[(row0 + row)*256 + d0];
    ushort4 h, lo;
    h.x = bfr(v.x); h.y = bfr(v.y); h.z = bfr(v.z); h.w = bfr(v.w);
    lo.x = bfr(v.x - bfu(h.x)); lo.y = bfr(v.y - bfu(h.y));
    lo.z = bfr(v.z - bfu(h.z)); lo.w = bfr(v.w - bfu(h.w));
    const int kt = d0 >> 5, lane = row | (((d0 >> 3) & 3) << 4), j = d0 & 7;
    *(ushort4*)&aF[0][kt*512 + lane*8 + j] = h;
    *(ushort4*)&aF[1][kt*512 + lane*8 + j] = lo;
  }
  __syncthreads();

  f32x4 acc[4];
  k4_gemm(acc, aF, wg, w, l64);
  #pragma unroll
  for (int nt = 0; nt < 4; ++nt) {
    const int cn = (w*4 + nt)*16 + col;
    #pragma unroll
    for (int r = 0; r < 4; ++r)
      bufB[(quad*4 + r)*260 + cn] = acc[nt][r] + rb2c[cn] + xtr[nt][r];
  }
  __syncthreads();
  {
    const int row = t >> 4, part = t & 15;
    float s = 0.f, s2 = 0.f;
    #pragma unroll
    for (int kk = 0; kk < 16; ++kk) {
      const float v = bufB[row*260 + part + kk*16];
      s += v; s2 = fmaf(v, v, s2);
    }
    #pragma unroll
    for (int off = 8; off; off >>= 1) {
      s  += __shfl_xor(s, off, 16);
      s2 += __shfl_xor(s2, off, 16);
    }
    if (part == 0) {
      const float mu = s * (1.f/256.f);
      mv[row][0] = mu;
      mv[row][1] = rsqrtf(fmaf(-mu, mu, s2 * (1.f/256.f)) + 1e-5f);
    }
  }
  __syncthreads();
  #pragma unroll
  for (int i = 0; i < 4; ++i) {
    const int c = t + i*256;
    const int row = c >> 6, d0 = (c & 63)*4;
    float4 v = *(const float4*)&bufB[row*260 + d0];
    const float m = mv[row][0], iv = mv[row][1];
    v.x = (v.x - m)*iv*lngc[d0]   + lnbc[d0];
    v.y = (v.y - m)*iv*lngc[d0+1] + lnbc[d0+1];
    v.z = (v.z - m)*iv*lngc[d0+2] + lnbc[d0+2];
    v.w = (v.w - m)*iv*lngc[d0+3] + lnbc[d0+3];
    ushort4 h, lo;
    h.x = bfr(v.x); h.y = bfr(v.y); h.z = bfr(v.z); h.w = bfr(v.w);
    lo.x = bfr(v.x - bfu(h.x)); lo.y = bfr(v.y - bfu(h.y));
    lo.z = bfr(v.z - bfu(h.z)); lo.w = bfr(v.w - bfu(h.w));
    const int kt = d0 >> 5, lane = row | (((d0 >> 3) & 3) << 4), j = d0 & 7;
    *(ushort4*)&aF[0][kt*512 + lane*8 + j] = h;
    *(ushort4*)&aF[1][kt*512 + lane*8 + j] = lo;
  }
  __syncthreads();
  k4_gemm(acc, aF, wg + 65536, w, l64);
  #pragma unroll
  for (int nt = 0; nt < 4; ++nt) {
    const int cn = (w*4 + nt)*16 + col;
    #pragma unroll
    for (int r = 0; r < 4; ++r)
      bufB[(quad*4 + r)*260 + cn] = gelu_e(acc[nt][r] + mb1c[cn]);
  }
  __syncthreads();
  #pragma unroll
  for (int i = 0; i < 4; ++i) {
    const int c = t + i*256;
    const int row = c >> 6, d0 = (c & 63)*4;
    const float4 v = *(const float4*)&bufB[row*260 + d0];
    ushort4 h, lo;
    h.x = bfr(v.x); h.y = bfr(v.y); h.z = bfr(v.z); h.w = bfr(v.w);
    lo.x = bfr(v.x - bfu(h.x)); lo.y = bfr(v.y - bfu(h.y));
    lo.z = bfr(v.z - bfu(h.z)); lo.w = bfr(v.w - bfu(h.w));
    const int kt = d0 >> 5, lane = row | (((d0 >> 3) & 3) << 4), j = d0 & 7;
    *(ushort4*)&aF[0][kt*512 + lane*8 + j] = h;
    *(ushort4*)&aF[1][kt*512 + lane*8 + j] = lo;
  }
  __syncthreads();
  k4_gemm(acc, aF, wg + 2*65536, w, l64);
  #pragma unroll
  for (int nt = 0; nt < 4; ++nt) {
    const int cn = (w*4 + nt)*16 + col;
    #pragma unroll
    for (int r = 0; r < 4; ++r)
      x[(row0 + quad*4 + r)*256 + cn] = acc[nt][r] + mb2c[cn] + xtr[nt][r];
  }
}

// ---------------------------------------------------------------------------
// k5: s=sum_K x ; h=gelu(s@projT+pb) ; mu=h@muT+mb ; scale=softplus(h@spT+sb)
// ---------------------------------------------------------------------------
__global__ __launch_bounds__(256) void k5_head(
    const float* __restrict__ x, const float* __restrict__ wh,
    const float* __restrict__ bc, const int* __restrict__ flag,
    void* __restrict__ out)
{
  __shared__ float ss[256];
  __shared__ float hh[128];
  const int b = blockIdx.x, t = threadIdx.x;
  const int fl = *flag;
  float s = 0.f;
  for (int i = 0; i < 64; ++i) s += x[((b << 6) + i)*256 + t];
  ss[t] = s;
  __syncthreads();
  if (t < 128) {
    float acc = bc[3072 + t];
    const float* projT = wh;
    for (int d = 0; d < 256; ++d) acc = fmaf(ss[d], projT[d*128 + t], acc);
    hh[t] = gelu_e(acc);
  }
  __syncthreads();
  float v; int oidx;
  if (t < 128) {
    float acc = bc[3200 + t];
    const float* muT = wh + 32768;
    for (int c = 0; c < 128; ++c) acc = fmaf(hh[c], muT[c*128 + t], acc);
    v = acc; oidx = b*128 + t;
  } else {
    const int u = t - 128;
    float acc = bc[3328 + u];
    const float* spT = wh + 49152;
    for (int c = 0; c < 128; ++c) acc = fmaf(hh[c], spT[c*128 + u], acc);
    v = (acc > 20.f) ? acc : log1pf(__expf(acc));
    oidx = 4096 + b*128 + u;
  }
  if (fl) ((bf16*)out)[oidx] = __float2bfloat16(v);
  else    ((float*)out)[oidx] = v;
}

// ---------------------------------------------------------------------------
extern "C" void kernel_launch(void* const* d_in, const int* in_sizes, int n_in,
                              void* d_out, int out_size, void* d_ws, size_t ws_size,
                              hipStream_t stream)
{
  (void)in_sizes; (void)n_in; (void)out_size; (void)ws_size;
  float* ws    = (float*)d_ws;
  int*   flag  = (int*)ws;
  float* x     = ws + 16;                          // 524288
  float* kq    = x + 524288;                       // 1048576
  float* Pf    = kq + 1048576;                     // 524288
  unsigned* Qpk = (unsigned*)(Pf + 524288);        // 262144
  float* g     = (float*)(Qpk + 262144);           // 524288
  float* attn  = g + 524288;                       // 131072
  unsigned short* wfb = (unsigned short*)(attn + 131072);  // 524288 shorts
  unsigned short* w3b = wfb + 524288;              // 393216 shorts
  float* wh    = (float*)(w3b + 393216);           // 65536
  float* bc    = wh + 65536;                       // 3456

  detect_kernel<<<dim3(1), dim3(256), 0, stream>>>(d_in[0], flag);
  prep_kernel<<<dim3(345), dim3(256), 0, stream>>>(
      d_in[0], d_in[1], d_in[2], d_in[3], d_in[5], d_in[9], d_in[11],
      d_in[13], d_in[15], d_in[17],
      d_in[4], d_in[6], d_in[7], d_in[8], d_in[10], d_in[12],
      d_in[14], d_in[16], d_in[18],
      flag, x, wfb, w3b, wh, bc);
  for (int l = 0; l < NL; ++l) {
    k1_kqpq<<<dim3(256), dim3(256), 0, stream>>>(x, wfb, bc, kq, Pf, Qpk, l);
    ks_scores<<<dim3(32), dim3(256), 0, stream>>>(kq, attn);
    k23_agg<<<dim3(512), dim3(256), 0, stream>>>(Pf, Qpk, attn, g);
    k4_mix<<<dim3(128), dim3(256), 0, stream>>>(g, w3b, bc, x, l);
  }
  k5_head<<<dim3(32), dim3(256), 0, stream>>>(x, wh, bc, flag, (void*)d_out);
}

// Round 7
// 213.772 us; speedup vs baseline: 1.1589x; 1.1589x over previous
//
#include <hip/hip_runtime.h>
#include <hip/hip_bf16.h>

#define NL 2
// B=32, K=64, D=256, LS=128, rows = B*K = 2048

using bf16 = __hip_bfloat16;
typedef short bf16x8 __attribute__((ext_vector_type(8)));
typedef float f32x4 __attribute__((ext_vector_type(4)));

__device__ __forceinline__ float bfu(unsigned short u) { return __uint_as_float(((unsigned)u) << 16); }

__device__ __forceinline__ unsigned short bfr(float v) {   // RNE fp32->bf16 bits
  unsigned u = __float_as_uint(v);
  u += 0x7FFFu + ((u >> 16) & 1u);
  return (unsigned short)(u >> 16);
}

// sigmoid-form gelu for the bulk sweep
__device__ __forceinline__ float gelu_s(float x) {
  float e = __expf(-1.702f * x);
  return x * __builtin_amdgcn_rcpf(1.0f + e);
}

// exact gelu for the low-volume spots
__device__ __forceinline__ float gelu_e(float x) {
  return 0.5f * x * (1.0f + erff(x * 0.7071067811865475f));
}

__device__ __forceinline__ float load_f(const void* p, int i, int fl) {
  if (fl) return bfu(((const unsigned short*)p)[i]);
  return ((const float*)p)[i];
}

// per-block inline dtype detect: 1 = inputs are bf16
__device__ __forceinline__ int block_detect(const void* X) {
  __shared__ int bad_s;
  if (threadIdx.x == 0) bad_s = 0;
  __syncthreads();
  if (threadIdx.x < 256) {
    const float v = bfu(((const unsigned short*)X)[threadIdx.x]);
    if (!(fabsf(v) < 1e6f)) atomicOr(&bad_s, 1);
  }
  __syncthreads();
  return bad_s ? 0 : 1;
}

// stage one float4 (row, d0) into hi/lo MFMA A-fragments
__device__ __forceinline__ void stage_split4(unsigned short (&aF)[2][4096], int row, int d0, float4 v) {
  ushort4 h, lo;
  h.x = bfr(v.x); h.y = bfr(v.y); h.z = bfr(v.z); h.w = bfr(v.w);
  lo.x = bfr(v.x - bfu(h.x)); lo.y = bfr(v.y - bfu(h.y));
  lo.z = bfr(v.z - bfu(h.z)); lo.w = bfr(v.w - bfu(h.w));
  const int kt = d0 >> 5, lane = row | (((d0 >> 3) & 3) << 4), j = d0 & 7;
  *(ushort4*)&aF[0][kt*512 + lane*8 + j] = h;
  *(ushort4*)&aF[1][kt*512 + lane*8 + j] = lo;
}

// ---------------------------------------------------------------------------
// prep: weights -> ws (inline dtype detect per block)
// blocks: [0,16) A: wfb frags (l,kt) | [16,64) B: w3b frags (l,gm,kt)
//         [64,88) D: wh transposes  | 88 E: bc biases
// ---------------------------------------------------------------------------
__global__ __launch_bounds__(256) void prep_kernel(
    const void* __restrict__ X, const void* __restrict__ kw, const void* __restrict__ qw,
    const void* __restrict__ rw1, const void* __restrict__ rw2, const void* __restrict__ mw1,
    const void* __restrict__ mw2, const void* __restrict__ pw, const void* __restrict__ muw,
    const void* __restrict__ spw,
    const void* __restrict__ rb1, const void* __restrict__ rb2, const void* __restrict__ lng,
    const void* __restrict__ lnb, const void* __restrict__ mb1, const void* __restrict__ mb2,
    const void* __restrict__ pb, const void* __restrict__ mub, const void* __restrict__ spb,
    unsigned short* __restrict__ wfb, unsigned short* __restrict__ w3b,
    float* __restrict__ wh, float* __restrict__ bc)
{
  __shared__ __align__(16) char psm[65536];
  const int fl = block_detect(X);
  const int t = threadIdx.x;
  int blk = blockIdx.x;

  if (blk < 16) {   // ---- A: wfb (l,kt)
    unsigned short* ls = (unsigned short*)psm;
    unsigned* lsu = (unsigned*)psm;
    const int l = blk >> 3, kt = blk & 7;
    if (fl) {
      #pragma unroll
      for (int s = 0; s < 4; ++s) {
        const unsigned* sp = (const unsigned*)((s == 0) ? kw : (s == 1) ? qw : rw1);
        const int rstr = (s < 2) ? 128 : 256;
        const int coff = ((s == 3) ? 128 : 0) + kt*16;
        for (int i = t; i < 4096; i += 256) {
          const int e = i >> 4, d2 = i & 15;
          lsu[s*4096 + i] = sp[(l*256 + e)*rstr + coff + d2];
        }
      }
    } else {
      #pragma unroll
      for (int s = 0; s < 4; ++s) {
        const float* sp = (const float*)((s == 0) ? kw : (s == 1) ? qw : rw1);
        const int rstr = (s < 2) ? 256 : 512;
        const int coff = ((s == 3) ? 256 : 0) + kt*32;
        for (int i = t; i < 4096; i += 256) {
          const int e = i >> 4, d2 = i & 15;
          const float f0 = sp[(l*256 + e)*rstr + coff + d2*2];
          const float f1 = sp[(l*256 + e)*rstr + coff + d2*2 + 1];
          lsu[s*4096 + i] = (unsigned)bfr(f0) | ((unsigned)bfr(f1) << 16);
        }
      }
    }
    __syncthreads();
    unsigned* outp = (unsigned*)wfb + (l*8 + kt)*16384;
    for (int f2 = t; f2 < 16384; f2 += 256) {
      const int j2 = f2 & 3, lane = (f2 >> 2) & 63, ntg = f2 >> 8;
      const int seg = ntg >> 4;
      const int e = (ntg & 15)*16 + (lane & 15);
      const int dl = ((lane >> 4) & 3)*8 + j2*2;
      unsigned short r0 = ls[seg*8192 + e*32 + dl];
      unsigned short r1 = ls[seg*8192 + e*32 + dl + 1];
      if (seg == 1) { r0 = bfr(bfu(r0)*0.0625f); r1 = bfr(bfu(r1)*0.0625f); }
      else if (seg == 2) {
        const unsigned short w0 = ls[3*8192 + e*32 + dl];
        const unsigned short w1 = ls[3*8192 + e*32 + dl + 1];
        r0 = bfr(bfu(r0) + bfu(w0)); r1 = bfr(bfu(r1) + bfu(w1));
      }
      outp[f2] = (unsigned)r0 | ((unsigned)r1 << 16);
    }
    return;
  }
  blk -= 16;
  if (blk < 48) {   // ---- B: w3b (l,gm,kt)
    unsigned short* ls = (unsigned short*)psm;
    unsigned* lsu = (unsigned*)psm;
    const int l3 = blk >> 3, kt = blk & 7;
    const int l = l3 / 3, gm = l3 % 3;
    const void* src = (gm == 0) ? rw2 : (gm == 1) ? mw1 : mw2;
    if (fl) {
      const unsigned* sp = (const unsigned*)src;
      for (int i = t; i < 4096; i += 256) {
        const int e = i >> 4, d2 = i & 15;
        lsu[i] = sp[(l*256 + e)*128 + kt*16 + d2];
      }
    } else {
      const float* sp = (const float*)src;
      for (int i = t; i < 4096; i += 256) {
        const int e = i >> 4, d2 = i & 15;
        const float f0 = sp[(l*256 + e)*256 + kt*32 + d2*2];
        const float f1 = sp[(l*256 + e)*256 + kt*32 + d2*2 + 1];
        lsu[i] = (unsigned)bfr(f0) | ((unsigned)bfr(f1) << 16);
      }
    }
    __syncthreads();
    unsigned* outp = (unsigned*)w3b + (l3*8 + kt)*4096;
    for (int f2 = t; f2 < 4096; f2 += 256) {
      const int j2 = f2 & 3, lane = (f2 >> 2) & 63, nt = f2 >> 8;
      const int e = nt*16 + (lane & 15);
      const int dl = ((lane >> 4) & 3)*8 + j2*2;
      outp[f2] = (unsigned)ls[e*32 + dl] | ((unsigned)ls[e*32 + dl + 1] << 16);
    }
    return;
  }
  blk -= 48;
  if (blk < 24) {   // ---- D: wh transposes
    float* lsf = (float*)psm;
    if (blk < 8) {          // projT
      const int l0 = blk*16;
      if (fl) {
        const unsigned* sp = (const unsigned*)pw;
        for (int i = t; i < 2048; i += 256) {
          const int ll = i >> 7, d2 = i & 127;
          const unsigned u = sp[(l0 + ll)*128 + d2];
          lsf[ll*256 + d2*2]     = __uint_as_float(u << 16);
          lsf[ll*256 + d2*2 + 1] = __uint_as_float(u & 0xffff0000u);
        }
      } else {
        const float* sp = (const float*)pw;
        for (int i = t; i < 4096; i += 256) {
          const int ll = i >> 8, d = i & 255;
          lsf[ll*256 + d] = sp[(l0 + ll)*256 + d];
        }
      }
      __syncthreads();
      for (int i = t; i < 4096; i += 256) {
        const int d = i >> 4, ll = i & 15;
        wh[d*128 + l0 + ll] = lsf[ll*256 + d];
      }
    } else {                // muT / spT
      const int grp = blk - 8;
      const int isSp = grp >> 3;
      const int l0 = (grp & 7)*16;
      const void* src = isSp ? spw : muw;
      const int off = isSp ? 49152 : 32768;
      if (fl) {
        const unsigned* sp = (const unsigned*)src;
        for (int i = t; i < 1024; i += 256) {
          const int ll = i >> 6, c2 = i & 63;
          const unsigned u = sp[(l0 + ll)*64 + c2];
          lsf[ll*128 + c2*2]     = __uint_as_float(u << 16);
          lsf[ll*128 + c2*2 + 1] = __uint_as_float(u & 0xffff0000u);
        }
      } else {
        const float* sp = (const float*)src;
        for (int i = t; i < 2048; i += 256) {
          const int ll = i >> 7, c = i & 127;
          lsf[ll*128 + c] = sp[(l0 + ll)*128 + c];
        }
      }
      __syncthreads();
      for (int i = t; i < 2048; i += 256) {
        const int c = i >> 4, ll = i & 15;
        wh[off + c*128 + l0 + ll] = lsf[ll*128 + c];
      }
    }
    return;
  }
  // ---- E: bc
  for (int i = t; i < 3456; i += 256) {
    const void* src; int off;
    if (i < 512)       { src = rb1; off = i; }
    else if (i < 1024) { src = rb2; off = i - 512; }
    else if (i < 1536) { src = lng; off = i - 1024; }
    else if (i < 2048) { src = lnb; off = i - 1536; }
    else if (i < 2560) { src = mb1; off = i - 2048; }
    else if (i < 3072) { src = mb2; off = i - 2560; }
    else if (i < 3200) { src = pb;  off = i - 3072; }
    else if (i < 3328) { src = mub; off = i - 3200; }
    else               { src = spb; off = i - 3328; }
    bc[i] = load_f(src, off, fl);
  }
}

// ---------------------------------------------------------------------------
// k1 body: 16 rows x 1024 cols from staged A-frags; 512 thr / 8 waves
//   outputs kq [2048][512] (k|q), Pf [2048][256] (+rb1), Qpk packed bf16
// ---------------------------------------------------------------------------
template<bool SPLIT>
__device__ __forceinline__ void k1_body(
    const unsigned short (&aF)[2][4096],
    const unsigned short* __restrict__ wfb, const float* __restrict__ bc,
    float* __restrict__ kq, float* __restrict__ Pf, unsigned* __restrict__ Qpk,
    int l, int row0, int t)
{
  const int w = t >> 6, l64 = t & 63;
  const int col = l64 & 15, quad = l64 >> 4;
  f32x4 acc[8];
  #pragma unroll
  for (int i = 0; i < 8; ++i) acc[i] = (f32x4){0.f, 0.f, 0.f, 0.f};
  for (int kt = 0; kt < 8; ++kt) {
    const bf16x8 ah = *(const bf16x8*)&aF[0][kt*512 + l64*8];
    bf16x8 al;
    if (SPLIT) al = *(const bf16x8*)&aF[1][kt*512 + l64*8];
    #pragma unroll
    for (int i = 0; i < 8; ++i) {
      const int ntg = w*8 + i;
      const bf16x8 b = *(const bf16x8*)&wfb[((l*8 + kt)*64 + ntg)*512 + l64*8];
      acc[i] = __builtin_amdgcn_mfma_f32_16x16x32_bf16(ah, b, acc[i], 0, 0, 0);
      if (SPLIT) acc[i] = __builtin_amdgcn_mfma_f32_16x16x32_bf16(al, b, acc[i], 0, 0, 0);
    }
  }
  #pragma unroll
  for (int i = 0; i < 8; ++i) {
    const int ntg = w*8 + i;
    if (ntg < 32) {
      const int n = ntg*16 + col;
      #pragma unroll
      for (int r = 0; r < 4; ++r)
        kq[(size_t)(row0 + quad*4 + r)*512 + n] = acc[i][r];
    } else if (ntg < 48) {
      const int c = (ntg - 32)*16 + col;
      const float bias = bc[l*256 + c];
      #pragma unroll
      for (int r = 0; r < 4; ++r)
        Pf[(size_t)(row0 + quad*4 + r)*256 + c] = acc[i][r] + bias;
    } else {
      #pragma unroll
      for (int r = 0; r < 4; ++r) {
        const float v = acc[i][r];
        const float pv = __shfl_xor(v, 1, 64);
        if (!(col & 1)) {
          const unsigned uu = (unsigned)bfr(v) | ((unsigned)bfr(pv) << 16);
          Qpk[(size_t)(row0 + quad*4 + r)*128 + (ntg - 48)*8 + (col >> 1)] = uu;
        }
      }
    }
  }
}

// ---------------------------------------------------------------------------
// k1 layer-0: stage X directly (bf16 -> hi-only, single MFMA; fp32 -> split)
// ---------------------------------------------------------------------------
__global__ __launch_bounds__(512) void k1l0(
    const void* __restrict__ X, const unsigned short* __restrict__ wfb,
    const float* __restrict__ bc, float* __restrict__ kq, float* __restrict__ Pf,
    unsigned* __restrict__ Qpk)
{
  const int fl = block_detect(X);
  __shared__ __align__(16) unsigned short aF[2][4096];
  const int t = threadIdx.x;
  const int row0 = blockIdx.x * 16;
  if (fl) {
    const int c = t;                         // 512 chunks of 8 bf16
    const int row = c >> 5, d0 = (c & 31) * 8;
    const uint4 u = *(const uint4*)((const unsigned*)X + (size_t)(row0 + row)*128 + (c & 31)*4);
    const int kt = d0 >> 5, lane = row | (((d0 >> 3) & 3) << 4);
    *(uint4*)&aF[0][kt*512 + lane*8] = u;
  } else {
    for (int i = t; i < 1024; i += 512) {
      const int row = i >> 6, d0 = (i & 63) * 4;
      const float4 v = *(const float4*)((const float*)X + (size_t)(row0 + row)*256 + d0);
      stage_split4(aF, row, d0, v);
    }
  }
  __syncthreads();
  if (fl) k1_body<false>(aF, wfb, bc, kq, Pf, Qpk, 0, row0, t);
  else    k1_body<true >(aF, wfb, bc, kq, Pf, Qpk, 0, row0, t);
}

// ---------------------------------------------------------------------------
// k23: fused scores + softmax + gelu-weighted aggregation
// grid 512 (b, i-quartet), 256 thr / 4 waves
// ---------------------------------------------------------------------------
__global__ __launch_bounds__(256) void k23_attn(
    const float* __restrict__ kq, const float* __restrict__ Pf,
    const unsigned* __restrict__ Qpk, float* __restrict__ g)
{
  __shared__ unsigned qls[8192];    // Qpk tile [j 64][cp 128]
  __shared__ float qs[4][256];      // q rows
  __shared__ float sc[4][64];
  __shared__ float als[4][64];
  const int t = threadIdx.x;
  const int b = (int)blockIdx.x >> 4, rq = (int)blockIdx.x & 15;
  const int base = b << 6, i0 = rq * 4;
  {
    const float4* src = (const float4*)(Qpk + (size_t)base*128);
    float4* dst = (float4*)qls;
    for (int i = t; i < 2048; i += 256) dst[i] = src[i];
  }
  for (int i = t; i < 1024; i += 256)
    qs[i >> 8][i & 255] = kq[(size_t)(base + i0 + (i >> 8))*512 + 256 + (i & 255)];
  __syncthreads();

  // scores: wave w -> j group; lane = (part<<4)|jl; each lane: 4 rows x 64 d
  {
    const int w = t >> 6, lane = t & 63;
    const int jl = lane & 15, part = lane >> 4;
    const int j = w*16 + jl;
    const float* krow = kq + (size_t)(base + j)*512 + part*64;
    float s0 = 0.f, s1 = 0.f, s2 = 0.f, s3 = 0.f;
    for (int dd = 0; dd < 64; dd += 4) {
      const float4 kv = *(const float4*)&krow[dd];
      const float4 q0 = *(const float4*)&qs[0][part*64 + dd];
      const float4 q1 = *(const float4*)&qs[1][part*64 + dd];
      const float4 q2 = *(const float4*)&qs[2][part*64 + dd];
      const float4 q3 = *(const float4*)&qs[3][part*64 + dd];
      s0 = fmaf(kv.x, q0.x, s0); s0 = fmaf(kv.y, q0.y, s0); s0 = fmaf(kv.z, q0.z, s0); s0 = fmaf(kv.w, q0.w, s0);
      s1 = fmaf(kv.x, q1.x, s1); s1 = fmaf(kv.y, q1.y, s1); s1 = fmaf(kv.z, q1.z, s1); s1 = fmaf(kv.w, q1.w, s1);
      s2 = fmaf(kv.x, q2.x, s2); s2 = fmaf(kv.y, q2.y, s2); s2 = fmaf(kv.z, q2.z, s2); s2 = fmaf(kv.w, q2.w, s2);
      s3 = fmaf(kv.x, q3.x, s3); s3 = fmaf(kv.y, q3.y, s3); s3 = fmaf(kv.z, q3.z, s3); s3 = fmaf(kv.w, q3.w, s3);
    }
    s0 += __shfl_xor(s0, 16, 64); s0 += __shfl_xor(s0, 32, 64);
    s1 += __shfl_xor(s1, 16, 64); s1 += __shfl_xor(s1, 32, 64);
    s2 += __shfl_xor(s2, 16, 64); s2 += __shfl_xor(s2, 32, 64);
    s3 += __shfl_xor(s3, 16, 64); s3 += __shfl_xor(s3, 32, 64);
    if (part == 0) { sc[0][j] = s0; sc[1][j] = s1; sc[2][j] = s2; sc[3][j] = s3; }
  }
  __syncthreads();
  {
    const int row = t >> 6, j = t & 63;    // one wave per row
    float s = sc[row][j];
    float m = s;
    #pragma unroll
    for (int off = 32; off; off >>= 1) m = fmaxf(m, __shfl_xor(m, off, 64));
    const float e = __expf(s - m);
    float ss = e;
    #pragma unroll
    for (int off = 32; off; off >>= 1) ss += __shfl_xor(ss, off, 64);
    als[row][j] = e / ss;
  }
  __syncthreads();

  // aggregation sweep
  const int rg = t >> 7, cp = t & 127;
  const int r0 = base + i0 + rg*2;
  const float2 P0 = *(const float2*)&Pf[(size_t)r0*256 + cp*2];
  const float2 P1 = *(const float2*)&Pf[(size_t)(r0 + 1)*256 + cp*2];
  const float A00 = -1.702f * P0.x, A01 = -1.702f * P0.y;
  const float A10 = -1.702f * P1.x, A11 = -1.702f * P1.y;
  const float* a0p = &als[rg*2][0];
  const float* a1p = &als[rg*2 + 1][0];
  float acc00 = 0.f, acc01 = 0.f, acc10 = 0.f, acc11 = 0.f;
  #pragma unroll 4
  for (int j = 0; j < 64; ++j) {
    const unsigned u = qls[j*128 + cp];
    const float w0 = a0p[j], w1 = a1p[j];
    const float q0 = __uint_as_float(u << 16);
    const float q1 = __uint_as_float(u & 0xffff0000u);
    const float s00 = __builtin_amdgcn_rcpf(1.f + __expf(fmaf(1.702f, q0, A00)));
    const float s01 = __builtin_amdgcn_rcpf(1.f + __expf(fmaf(1.702f, q1, A01)));
    const float s10 = __builtin_amdgcn_rcpf(1.f + __expf(fmaf(1.702f, q0, A10)));
    const float s11 = __builtin_amdgcn_rcpf(1.f + __expf(fmaf(1.702f, q1, A11)));
    acc00 = fmaf(w0 * (P0.x - q0), s00, acc00);
    acc01 = fmaf(w0 * (P0.y - q1), s01, acc01);
    acc10 = fmaf(w1 * (P1.x - q0), s10, acc10);
    acc11 = fmaf(w1 * (P1.y - q1), s11, acc11);
  }
  *(float2*)&g[(size_t)r0*256 + cp*2]       = make_float2(acc00, acc01);
  *(float2*)&g[(size_t)(r0 + 1)*256 + cp*2] = make_float2(acc10, acc11);
}

// ---------------------------------------------------------------------------
// k4 core (512 thr / 8 waves): agg=g@rw2^T+rb2; h=LN(xin+agg); out=xin+mlp(h)
// TAIL: leave x_new staged as A-frags in aF and write xout coalesced
// ---------------------------------------------------------------------------
__device__ __forceinline__ void k4_gemm8(
    f32x4 acc[2], const unsigned short (&aF)[2][4096],
    const unsigned short* __restrict__ wg, int w, int l64)
{
  acc[0] = (f32x4){0.f, 0.f, 0.f, 0.f};
  acc[1] = (f32x4){0.f, 0.f, 0.f, 0.f};
  for (int kt = 0; kt < 8; ++kt) {
    const bf16x8 ah = *(const bf16x8*)&aF[0][kt*512 + l64*8];
    const bf16x8 al = *(const bf16x8*)&aF[1][kt*512 + l64*8];
    #pragma unroll
    for (int nt = 0; nt < 2; ++nt) {
      const bf16x8 b = *(const bf16x8*)&wg[((kt*16 + (w*2 + nt))*64 + l64)*8];
      acc[nt] = __builtin_amdgcn_mfma_f32_16x16x32_bf16(ah, b, acc[nt], 0, 0, 0);
      acc[nt] = __builtin_amdgcn_mfma_f32_16x16x32_bf16(al, b, acc[nt], 0, 0, 0);
    }
  }
}

template<bool ADAPT, bool TAIL>
__device__ __forceinline__ void k4_core(
    const float* __restrict__ g, const void* __restrict__ xin, int fl,
    float* __restrict__ xout, const unsigned short* __restrict__ wg,
    const float* __restrict__ bc, int l, int row0, int t,
    unsigned short (&aF)[2][4096], float* bufB, float (&mv)[16][2])
{
  const int w = t >> 6, l64 = t & 63;
  const int col = l64 & 15, quad = l64 >> 4;
  const float* rb2c = bc + 512  + l*256;
  const float* lngc = bc + 1024 + l*256;
  const float* lnbc = bc + 1536 + l*256;
  const float* mb1c = bc + 2048 + l*256;
  const float* mb2c = bc + 2560 + l*256;

  // stage g -> aF ; xin -> bufB (both coalesced)
  for (int i = t; i < 1024; i += 512) {
    const int row = i >> 6, d0 = (i & 63) * 4;
    stage_split4(aF, row, d0, *(const float4*)&g[(size_t)(row0 + row)*256 + d0]);
  }
  if (ADAPT && fl) {
    for (int c = t; c < 2048; c += 512) {
      const int row = c >> 7, dp = c & 127;
      const unsigned u = ((const unsigned*)xin)[(size_t)(row0 + row)*128 + dp];
      bufB[row*260 + dp*2]     = __uint_as_float(u << 16);
      bufB[row*260 + dp*2 + 1] = __uint_as_float(u & 0xffff0000u);
    }
  } else {
    for (int c = t; c < 1024; c += 512) {
      const int row = c >> 6, d0 = (c & 63) * 4;
      *(float4*)&bufB[row*260 + d0] = *(const float4*)((const float*)xin + (size_t)(row0 + row)*256 + d0);
    }
  }
  __syncthreads();
  float xtr[2][4];
  #pragma unroll
  for (int nt = 0; nt < 2; ++nt) {
    const int cn = (w*2 + nt)*16 + col;
    #pragma unroll
    for (int r = 0; r < 4; ++r) xtr[nt][r] = bufB[(quad*4 + r)*260 + cn];
  }
  __syncthreads();

  f32x4 acc[2];
  k4_gemm8(acc, aF, wg, w, l64);               // GEMM1
  #pragma unroll
  for (int nt = 0; nt < 2; ++nt) {
    const int cn = (w*2 + nt)*16 + col;
    #pragma unroll
    for (int r = 0; r < 4; ++r)
      bufB[(quad*4 + r)*260 + cn] = acc[nt][r] + rb2c[cn] + xtr[nt][r];
  }
  __syncthreads();
  {                                            // LN stats
    const int row = t >> 5, part = t & 31;
    float s = 0.f, s2 = 0.f;
    #pragma unroll
    for (int kk = 0; kk < 8; ++kk) {
      const float v = bufB[row*260 + part + kk*32];
      s += v; s2 = fmaf(v, v, s2);
    }
    #pragma unroll
    for (int off = 16; off; off >>= 1) {
      s  += __shfl_xor(s, off, 32);
      s2 += __shfl_xor(s2, off, 32);
    }
    if (part == 0) {
      const float mu = s * (1.f/256.f);
      mv[row][0] = mu;
      mv[row][1] = rsqrtf(fmaf(-mu, mu, s2 * (1.f/256.f)) + 1e-5f);
    }
  }
  __syncthreads();
  for (int i = t; i < 1024; i += 512) {        // LN apply + restage
    const int row = i >> 6, d0 = (i & 63) * 4;
    float4 v = *(const float4*)&bufB[row*260 + d0];
    const float m = mv[row][0], iv = mv[row][1];
    v.x = (v.x - m)*iv*lngc[d0]   + lnbc[d0];
    v.y = (v.y - m)*iv*lngc[d0+1] + lnbc[d0+1];
    v.z = (v.z - m)*iv*lngc[d0+2] + lnbc[d0+2];
    v.w = (v.w - m)*iv*lngc[d0+3] + lnbc[d0+3];
    stage_split4(aF, row, d0, v);
  }
  __syncthreads();
  k4_gemm8(acc, aF, wg + 65536, w, l64);       // GEMM2 + gelu
  #pragma unroll
  for (int nt = 0; nt < 2; ++nt) {
    const int cn = (w*2 + nt)*16 + col;
    #pragma unroll
    for (int r = 0; r < 4; ++r)
      bufB[(quad*4 + r)*260 + cn] = gelu_e(acc[nt][r] + mb1c[cn]);
  }
  __syncthreads();
  for (int i = t; i < 1024; i += 512) {        // restage
    const int row = i >> 6, d0 = (i & 63) * 4;
    stage_split4(aF, row, d0, *(const float4*)&bufB[row*260 + d0]);
  }
  __syncthreads();
  k4_gemm8(acc, aF, wg + 2*65536, w, l64);     // GEMM3 + residual
  if (TAIL) {
    #pragma unroll
    for (int nt = 0; nt < 2; ++nt) {
      const int cn = (w*2 + nt)*16 + col;
      #pragma unroll
      for (int r = 0; r < 4; ++r)
        bufB[(quad*4 + r)*260 + cn] = acc[nt][r] + mb2c[cn] + xtr[nt][r];
    }
    __syncthreads();
    for (int i = t; i < 1024; i += 512) {      // coalesced x write + restage for k1
      const int row = i >> 6, d0 = (i & 63) * 4;
      const float4 v = *(const float4*)&bufB[row*260 + d0];
      *(float4*)&xout[(size_t)(row0 + row)*256 + d0] = v;
      stage_split4(aF, row, d0, v);
    }
    __syncthreads();
  } else {
    #pragma unroll
    for (int nt = 0; nt < 2; ++nt) {
      const int cn = (w*2 + nt)*16 + col;
      #pragma unroll
      for (int r = 0; r < 4; ++r)
        xout[(size_t)(row0 + quad*4 + r)*256 + cn] = acc[nt][r] + mb2c[cn] + xtr[nt][r];
    }
  }
}

// k41: layer-0 mix (residual from X, adaptive) fused with layer-1 k1
__global__ __launch_bounds__(512) void k41_mix_kq(
    const float* __restrict__ g, const unsigned short* __restrict__ w3b,
    const unsigned short* __restrict__ wfb, const float* __restrict__ bc,
    const void* __restrict__ X, float* __restrict__ x,
    float* __restrict__ kq, float* __restrict__ Pf, unsigned* __restrict__ Qpk)
{
  const int fl = block_detect(X);
  __shared__ __align__(16) unsigned short aF[2][4096];
  __shared__ float bufB[16*260];
  __shared__ float mv[16][2];
  const int t = threadIdx.x;
  const int row0 = blockIdx.x * 16;
  k4_core<true, true>(g, X, fl, x, w3b, bc, 0, row0, t, aF, bufB, mv);
  k1_body<true>(aF, wfb, bc, kq, Pf, Qpk, 1, row0, t);
}

// k4fin: layer-1 mix only (x fp32 in/out)
__global__ __launch_bounds__(512) void k4_fin(
    const float* __restrict__ g, const unsigned short* __restrict__ w3b,
    const float* __restrict__ bc, float* __restrict__ x)
{
  __shared__ __align__(16) unsigned short aF[2][4096];
  __shared__ float bufB[16*260];
  __shared__ float mv[16][2];
  const int t = threadIdx.x;
  const int row0 = blockIdx.x * 16;
  k4_core<false, false>(g, x, 0, x, w3b + 3*65536, bc, 1, row0, t, aF, bufB, mv);
}

// ---------------------------------------------------------------------------
// k5: s=sum_K x ; h=gelu(s@projT+pb) ; mu=h@muT+mb ; scale=softplus(h@spT+sb)
// ---------------------------------------------------------------------------
__global__ __launch_bounds__(256) void k5_head(
    const float* __restrict__ x, const float* __restrict__ wh,
    const float* __restrict__ bc, const void* __restrict__ X,
    void* __restrict__ out)
{
  const int fl = block_detect(X);
  __shared__ float ss[256];
  __shared__ float hh[128];
  const int b = blockIdx.x, t = threadIdx.x;
  float s = 0.f;
  for (int i = 0; i < 64; ++i) s += x[(size_t)((b << 6) + i)*256 + t];
  ss[t] = s;
  __syncthreads();
  if (t < 128) {
    float acc = bc[3072 + t];
    const float* projT = wh;
    for (int d = 0; d < 256; ++d) acc = fmaf(ss[d], projT[d*128 + t], acc);
    hh[t] = gelu_e(acc);
  }
  __syncthreads();
  float v; int oidx;
  if (t < 128) {
    float acc = bc[3200 + t];
    const float* muT = wh + 32768;
    for (int c = 0; c < 128; ++c) acc = fmaf(hh[c], muT[c*128 + t], acc);
    v = acc; oidx = b*128 + t;
  } else {
    const int u = t - 128;
    float acc = bc[3328 + u];
    const float* spT = wh + 49152;
    for (int c = 0; c < 128; ++c) acc = fmaf(hh[c], spT[c*128 + u], acc);
    v = (acc > 20.f) ? acc : log1pf(__expf(acc));
    oidx = 4096 + b*128 + u;
  }
  if (fl) ((bf16*)out)[oidx] = __float2bfloat16(v);
  else    ((float*)out)[oidx] = v;
}

// ---------------------------------------------------------------------------
extern "C" void kernel_launch(void* const* d_in, const int* in_sizes, int n_in,
                              void* d_out, int out_size, void* d_ws, size_t ws_size,
                              hipStream_t stream)
{
  (void)in_sizes; (void)n_in; (void)out_size; (void)ws_size;
  float* ws    = (float*)d_ws;
  float* x     = ws + 16;                          // 524288
  float* kq    = x + 524288;                       // 1048576
  float* Pf    = kq + 1048576;                     // 524288
  unsigned* Qpk = (unsigned*)(Pf + 524288);        // 262144
  float* g     = (float*)(Qpk + 262144);           // 524288
  unsigned short* wfb = (unsigned short*)(g + 524288);   // 524288 shorts
  unsigned short* w3b = wfb + 524288;              // 393216 shorts
  float* wh    = (float*)(w3b + 393216);           // 65536
  float* bc    = wh + 65536;                       // 3456

  prep_kernel<<<dim3(89), dim3(256), 0, stream>>>(
      d_in[0], d_in[1], d_in[2], d_in[3], d_in[5], d_in[9], d_in[11],
      d_in[13], d_in[15], d_in[17],
      d_in[4], d_in[6], d_in[7], d_in[8], d_in[10], d_in[12],
      d_in[14], d_in[16], d_in[18],
      wfb, w3b, wh, bc);
  k1l0<<<dim3(128), dim3(512), 0, stream>>>(d_in[0], wfb, bc, kq, Pf, Qpk);
  k23_attn<<<dim3(512), dim3(256), 0, stream>>>(kq, Pf, Qpk, g);
  k41_mix_kq<<<dim3(128), dim3(512), 0, stream>>>(g, w3b, wfb, bc, d_in[0], x, kq, Pf, Qpk);
  k23_attn<<<dim3(512), dim3(256), 0, stream>>>(kq, Pf, Qpk, g);
  k4_fin<<<dim3(128), dim3(512), 0, stream>>>(g, w3b, bc, x);
  k5_head<<<dim3(32), dim3(256), 0, stream>>>(x, wh, bc, d_in[0], (void*)d_out);
}